// Round 4
// baseline (642.258 us; speedup 1.0000x reference)
//
#include <hip/hip_runtime.h>

typedef unsigned short ushort_t;
typedef unsigned char u8;
typedef short bf16x8 __attribute__((ext_vector_type(8)));
typedef float f32x4 __attribute__((ext_vector_type(4)));

#define T_DIM 4
#define B_DIM 32
#define C_DIM 512
#define N_DIM 256

__device__ __forceinline__ float bf2f(ushort_t u) {
  union { unsigned int i; float f; } x;
  x.i = ((unsigned int)u) << 16;
  return x.f;
}
__device__ __forceinline__ ushort_t f2bf(float f) {
  unsigned int u = __float_as_uint(f);
  u = (u + 0x7FFFu + ((u >> 16) & 1u)) >> 16;
  return (ushort_t)u;
}

// ---------------------------------------------------------------------------
// K0: split fp32 weights into 3 bf16 planes (hi, mid, lo). W ~= hi+mid+lo
// to ~2^-27 relative: MFMA with exact 0/1 spikes then matches fp32 math.
// Sqkv: [branch][plane][512][512] bf16 ; Sp: [plane][512][512] bf16
// ---------------------------------------------------------------------------
__global__ __launch_bounds__(256) void k0_split(
    const float* __restrict__ Wq, const float* __restrict__ Wk,
    const float* __restrict__ Wv, const float* __restrict__ Wp,
    ushort_t* __restrict__ Sqkv, ushort_t* __restrict__ Sp)
{
  int gid = blockIdx.x * 256 + threadIdx.x;   // [0, 131072)
  int w = gid >> 15;                          // 32768 threads per weight
  int off = (gid & 32767) * 8;
  const float* src = (w == 0) ? Wq : ((w == 1) ? Wk : ((w == 2) ? Wv : Wp));
  ushort_t* dst = (w < 3) ? (Sqkv + (size_t)w * 3 * 262144) : Sp;
  float wv[8];
  *(float4*)&wv[0] = *(const float4*)(src + off);
  *(float4*)&wv[4] = *(const float4*)(src + off + 4);
  ushort_t hi[8], mi[8], lo[8];
#pragma unroll
  for (int i = 0; i < 8; i++) {
    float f = wv[i];
    ushort_t h = f2bf(f);  float r  = f - bf2f(h);
    ushort_t m = f2bf(r);  float r2 = r - bf2f(m);
    ushort_t l = f2bf(r2);
    hi[i] = h; mi[i] = m; lo[i] = l;
  }
  *(uint4*)(dst + off)              = *(uint4*)&hi[0];
  *(uint4*)(dst + 262144 + off)     = *(uint4*)&mi[0];
  *(uint4*)(dst + 2 * 262144 + off) = *(uint4*)&lo[0];
}

// ---------------------------------------------------------------------------
// K1: shortcut LIF on x [T,B,C,N] (fp32) -> spikes transposed xsT8 [T,B,N,C] u8
// v' = v + (x - v)*0.5 (exact-halving == np's /2) ; s = v'>=1 ; v = s?0:v'
// ---------------------------------------------------------------------------
__global__ __launch_bounds__(256) void k1_shortcut_lif(
    const float* __restrict__ x, u8* __restrict__ xsT8)
{
  const int n0 = blockIdx.x * 64;
  const int c0 = blockIdx.y * 64;
  const int b  = blockIdx.z;
  __shared__ u8 sm[64][80];         // sm[n_local][c_local]
  const int tid = threadIdx.x;
  const int r  = tid >> 2;          // 0..63
  const int j0 = (tid & 3) * 16;    // 16-wide chunk
  float v[16];
#pragma unroll
  for (int i = 0; i < 16; i++) v[i] = 0.f;
  for (int t = 0; t < T_DIM; t++) {
    const float* xp = x + ((((size_t)t * B_DIM + b) * C_DIM) + c0 + r) * N_DIM + n0 + j0;
    float xv[16];
    *(float4*)&xv[0]  = *(const float4*)xp;
    *(float4*)&xv[4]  = *(const float4*)(xp + 4);
    *(float4*)&xv[8]  = *(const float4*)(xp + 8);
    *(float4*)&xv[12] = *(const float4*)(xp + 12);
    __syncthreads();   // guard previous iteration's LDS reads
#pragma unroll
    for (int i = 0; i < 16; i++) {
      float nv = v[i] + (xv[i] - v[i]) * 0.5f;
      bool s = (nv >= 1.0f);
      v[i] = s ? 0.f : nv;
      sm[j0 + i][r] = s ? (u8)1 : (u8)0;   // transpose into LDS
    }
    __syncthreads();
    union { uint4 u; u8 b[16]; } ov;
#pragma unroll
    for (int i = 0; i < 16; i++) ov.b[i] = sm[r][j0 + i];
    u8* op = xsT8 + ((((size_t)t * B_DIM + b) * N_DIM) + n0 + r) * C_DIM + c0 + j0;
    *(uint4*)op = ov.u;
  }
}

// ---------------------------------------------------------------------------
// K2: QKV conv1x1 + BN + LIF (t-loop fused, v-state in registers).
// A = split weights (3 bf16 planes), B = xsT8 spikes (u8 -> bf16 at staging).
// 128x128 tile, K=512, BK=32, MFMA 16x16x32 x 3 planes.
//    q -> qs8[t,b,c,n] u8 ; k -> ks8[t,b,c,n] u8
//    v -> vout[t,b,head,n,d] fp32 0/1 (the reference's returned v = out1)
// ---------------------------------------------------------------------------
__global__ __launch_bounds__(256, 2) void k2_qkv(
    const u8* __restrict__ xsT8, const ushort_t* __restrict__ Sqkv,
    const float* __restrict__ qsc, const float* __restrict__ qbi,
    const float* __restrict__ ksc, const float* __restrict__ kbi,
    const float* __restrict__ vsc, const float* __restrict__ vbi,
    u8* __restrict__ qs8, u8* __restrict__ ks8, float* __restrict__ vout)
{
  const int nt = blockIdx.x;          // 0..1   (n tile)
  const int mt = blockIdx.y;          // 0..11  (m tile over stacked 1536)
  const int b  = blockIdx.z;          // 0..31
  const int branch = mt >> 2;         // 0=q 1=k 2=v
  const int mloc = (mt & 3) * 128;
  const ushort_t* Ws = Sqkv + (size_t)branch * 3 * 262144;   // [plane][512][512]
  const float* scp = (branch == 0) ? qsc : ((branch == 1) ? ksc : vsc);
  const float* bip = (branch == 0) ? qbi : ((branch == 1) ? kbi : vbi);

  __shared__ ushort_t As3[3][128][40];   // [plane][m][k]
  __shared__ ushort_t Bs[128][40];       // [n][k]

  const int tid  = threadIdx.x;
  const int lane = tid & 63;
  const int wave = tid >> 6;
  const int wrow = (wave >> 1) * 64;
  const int wcol = (wave & 1) * 64;
  const int frow = lane & 15;
  const int fko  = (lane >> 4) * 8;

  f32x4 acc[16];
  float vst[64];
#pragma unroll
  for (int i = 0; i < 64; i++) vst[i] = 0.f;

  for (int t = 0; t < T_DIM; t++) {
#pragma unroll
    for (int i = 0; i < 16; i++) acc[i] = (f32x4){0.f, 0.f, 0.f, 0.f};
    const u8* Bbase = xsT8 + (((size_t)t * B_DIM + b) * N_DIM + nt * 128) * C_DIM;
    for (int kk = 0; kk < 512; kk += 32) {
      __syncthreads();
      // stage A: 3 planes x 128 x 32 bf16 = 1536 chunks of 8
#pragma unroll
      for (int u = 0; u < 6; u++) {
        int chunk = tid + u * 256;
        int p   = chunk >> 9;
        int rem = chunk & 511;
        int row = rem >> 2;
        int ko  = (rem & 3) * 8;
        *(uint4*)&As3[p][row][ko] =
          *(const uint4*)(Ws + (size_t)p * 262144 + (size_t)(mloc + row) * 512 + kk + ko);
      }
      // stage B: 128x32 u8 spikes -> bf16
      {
        int row = tid >> 1;          // 0..127
        int ko  = (tid & 1) * 16;
        union { uint4 u; u8 bvec[16]; } raw;
        raw.u = *(const uint4*)(Bbase + (size_t)row * 512 + kk + ko);
        ushort_t tmp[16];
#pragma unroll
        for (int i = 0; i < 16; i++) tmp[i] = raw.bvec[i] ? (ushort_t)0x3F80u : (ushort_t)0u;
        *(uint4*)&Bs[row][ko]     = *(uint4*)&tmp[0];
        *(uint4*)&Bs[row][ko + 8] = *(uint4*)&tmp[8];
      }
      __syncthreads();
      bf16x8 bfr[4];
#pragma unroll
      for (int j = 0; j < 4; j++) bfr[j] = *(const bf16x8*)&Bs[wcol + j * 16 + frow][fko];
#pragma unroll
      for (int p = 0; p < 3; p++) {
        bf16x8 af[4];
#pragma unroll
        for (int i = 0; i < 4; i++) af[i] = *(const bf16x8*)&As3[p][wrow + i * 16 + frow][fko];
#pragma unroll
        for (int i = 0; i < 4; i++)
#pragma unroll
          for (int j = 0; j < 4; j++)
            acc[i * 4 + j] = __builtin_amdgcn_mfma_f32_16x16x32_bf16(af[i], bfr[j], acc[i * 4 + j], 0, 0, 0);
      }
    }
    // epilogue: BN + LIF, write spikes
    const int crow0 = (lane >> 4) * 4;
    const int cn    = lane & 15;
    const size_t tb = (size_t)t * B_DIM + b;
#pragma unroll
    for (int i = 0; i < 4; i++) {
#pragma unroll
      for (int r = 0; r < 4; r++) {
        int c = mloc + wrow + i * 16 + crow0 + r;
        float sc = scp[c];
        float bi = bip[c];
#pragma unroll
        for (int j = 0; j < 4; j++) {
          int n = nt * 128 + wcol + j * 16 + cn;
          float y = acc[i * 4 + j][r] * sc + bi;
          int vi = (i * 4 + j) * 4 + r;
          float v = vst[vi];
          v = v + (y - v) * 0.5f;
          bool s = (v >= 1.0f);
          vst[vi] = s ? 0.f : v;
          if (branch == 0) {
            qs8[(tb * C_DIM + c) * N_DIM + n] = s ? (u8)1 : (u8)0;
          } else if (branch == 1) {
            ks8[(tb * C_DIM + c) * N_DIM + n] = s ? (u8)1 : (u8)0;
          } else {
            vout[((tb * 8 + (c >> 6)) * N_DIM + n) * 64 + (c & 63)] = s ? 1.0f : 0.0f;
          }
        }
      }
    }
  }
}

// ---------------------------------------------------------------------------
// K3: attn[ch,b,h,d,e] = (1/16) * sum_{t in chunk, n} k[d,(t,n)] * v[(t,n),e]
// k from ks8 (u8); v from out1 (fp32 0/1). Integer sums -> fp32 exact.
// ---------------------------------------------------------------------------
__global__ __launch_bounds__(256) void k3_attn(
    const u8* __restrict__ ks8, const float* __restrict__ vsp,
    float* __restrict__ attn)
{
  const int h  = blockIdx.x;
  const int b  = blockIdx.y;
  const int ch = blockIdx.z;
  __shared__ u8 KtT[64][80];       // [s][d]
  __shared__ u8 Vt[64][80];        // [s][e]
  const int tid = threadIdx.x;
  const int d0 = (tid >> 4) * 4;
  const int e0 = (tid & 15) * 4;
  float a[16];
#pragma unroll
  for (int i = 0; i < 16; i++) a[i] = 0.f;

  for (int tt = 0; tt < 2; tt++) {
    int t = ch * 2 + tt;
    for (int n0 = 0; n0 < 256; n0 += 64) {
      __syncthreads();
      {
        // k spikes: global [d][s] -> LDS [s][d]
        int d  = tid >> 2;
        int s0 = (tid & 3) * 16;
        union { uint4 u; u8 bvec[16]; } kb;
        kb.u = *(const uint4*)(ks8 + ((((size_t)t * B_DIM + b) * C_DIM) + h * 64 + d) * N_DIM + n0 + s0);
#pragma unroll
        for (int i = 0; i < 16; i++) KtT[s0 + i][d] = kb.bvec[i];
      }
      {
        // v spikes: fp32 [n][e] -> u8 LDS [s][e]
        const float* vb = vsp + ((((size_t)t * B_DIM + b) * 8 + h) * N_DIM + n0) * 64;
#pragma unroll
        for (int u = 0; u < 4; u++) {
          int chunk = tid + u * 256;       // [0,1024)
          int row = chunk >> 4;            // 0..63
          int eo  = (chunk & 15) * 4;
          float4 v4 = *(const float4*)(vb + (size_t)row * 64 + eo);
          Vt[row][eo + 0] = (u8)(v4.x != 0.f);
          Vt[row][eo + 1] = (u8)(v4.y != 0.f);
          Vt[row][eo + 2] = (u8)(v4.z != 0.f);
          Vt[row][eo + 3] = (u8)(v4.w != 0.f);
        }
      }
      __syncthreads();
      for (int s = 0; s < 64; s++) {
        uchar4 kb = *(const uchar4*)&KtT[s][d0];
        float kv[4] = { (float)kb.x, (float)kb.y, (float)kb.z, (float)kb.w };
        uchar4 vr = *(const uchar4*)&Vt[s][e0];
        float vv[4] = { (float)vr.x, (float)vr.y, (float)vr.z, (float)vr.w };
#pragma unroll
        for (int i = 0; i < 4; i++)
#pragma unroll
          for (int j = 0; j < 4; j++) a[i * 4 + j] += kv[i] * vv[j];
      }
    }
  }
  float* ap = attn + ((((size_t)ch * B_DIM + b) * 8 + h) * 64 + d0) * 64 + e0;
#pragma unroll
  for (int i = 0; i < 4; i++)
#pragma unroll
    for (int j = 0; j < 4; j++)
      ap[i * 64 + j] = a[i * 4 + j] * 0.0625f;   // * 1/H, exact
}

// ---------------------------------------------------------------------------
// K4: out[e,n] = sum_d attn[d,e]*q[d,n] (exact multiples of 1/16), LIF(0.5),
// spikes -> x2sT8[t,b,n,c=h*64+e] u8.
// ---------------------------------------------------------------------------
__global__ __launch_bounds__(256) void k4_out_lif(
    const u8* __restrict__ qs8, const float* __restrict__ attn,
    u8* __restrict__ x2sT8)
{
  const int h = blockIdx.x;
  const int b = blockIdx.y;
  __shared__ float At[64][68];
  __shared__ u8 Qt[64][80];
  const int tid = threadIdx.x;
  const int e0 = (tid >> 4) * 4;
  const int n0 = (tid & 15) * 4;
  float vst[64];
#pragma unroll
  for (int i = 0; i < 64; i++) vst[i] = 0.f;

  for (int t = 0; t < T_DIM; t++) {
    if ((t & 1) == 0) {
      __syncthreads();
      const float* ap = attn + ((((size_t)(t >> 1) * B_DIM + b) * 8) + h) * 4096;
      int dr = tid >> 2;
      int co = (tid & 3) * 16;
#pragma unroll
      for (int u = 0; u < 4; u++)
        *(float4*)&At[dr][co + u * 4] = *(const float4*)(ap + dr * 64 + co + u * 4);
    }
    for (int nc = 0; nc < 4; nc++) {
      __syncthreads();
      {
        int d  = tid >> 2;
        int so = (tid & 3) * 16;
        *(uint4*)&Qt[d][so] =
          *(const uint4*)(qs8 + ((((size_t)t * B_DIM + b) * C_DIM) + h * 64 + d) * N_DIM + nc * 64 + so);
      }
      __syncthreads();
      float acc[16];
#pragma unroll
      for (int i = 0; i < 16; i++) acc[i] = 0.f;
      for (int d = 0; d < 64; d++) {
        float4 av = *(const float4*)&At[d][e0];
        float avv[4] = { av.x, av.y, av.z, av.w };
        uchar4 qr = *(const uchar4*)&Qt[d][n0];
        float qv[4] = { (float)qr.x, (float)qr.y, (float)qr.z, (float)qr.w };
#pragma unroll
        for (int i = 0; i < 4; i++)
#pragma unroll
          for (int j = 0; j < 4; j++) acc[i * 4 + j] += avv[i] * qv[j];
      }
#pragma unroll
      for (int j = 0; j < 4; j++) {
        u8 sv[4];
#pragma unroll
        for (int i = 0; i < 4; i++) {
          int vi = nc * 16 + i * 4 + j;
          float y = acc[i * 4 + j];
          float nv = vst[vi] + (y - vst[vi]) * 0.5f;
          bool s = (nv >= 0.5f);
          vst[vi] = s ? 0.f : nv;
          sv[i] = s ? (u8)1 : (u8)0;
        }
        int n = nc * 64 + n0 + j;
        u8* op = x2sT8 + ((((size_t)t * B_DIM + b) * N_DIM) + n) * C_DIM + h * 64 + e0;
        *(uchar4*)op = make_uchar4(sv[0], sv[1], sv[2], sv[3]);
      }
    }
  }
}

// ---------------------------------------------------------------------------
// K5: proj conv1x1 (+bp) *scale +bias + residual x -> out0[t,b,c,n] fp32
// ---------------------------------------------------------------------------
__global__ __launch_bounds__(256, 2) void k5_proj(
    const u8* __restrict__ x2sT8, const ushort_t* __restrict__ Sp,
    const float* __restrict__ bp, const float* __restrict__ psc,
    const float* __restrict__ pbi,
    const float* __restrict__ x, float* __restrict__ out0)
{
  const int nt = blockIdx.x;   // 0..1
  const int mt = blockIdx.y;   // 0..3
  const int tb = blockIdx.z;   // 0..127
  __shared__ ushort_t As3[3][128][40];
  __shared__ ushort_t Bs[128][40];
  const int tid  = threadIdx.x;
  const int lane = tid & 63;
  const int wave = tid >> 6;
  const int wrow = (wave >> 1) * 64;
  const int wcol = (wave & 1) * 64;
  const int frow = lane & 15;
  const int fko  = (lane >> 4) * 8;
  f32x4 acc[16];
#pragma unroll
  for (int i = 0; i < 16; i++) acc[i] = (f32x4){0.f, 0.f, 0.f, 0.f};
  const u8* Bbase = x2sT8 + ((size_t)tb * N_DIM + nt * 128) * C_DIM;
  for (int kk = 0; kk < 512; kk += 32) {
    __syncthreads();
#pragma unroll
    for (int u = 0; u < 6; u++) {
      int chunk = tid + u * 256;
      int p   = chunk >> 9;
      int rem = chunk & 511;
      int row = rem >> 2;
      int ko  = (rem & 3) * 8;
      *(uint4*)&As3[p][row][ko] =
        *(const uint4*)(Sp + (size_t)p * 262144 + (size_t)(mt * 128 + row) * 512 + kk + ko);
    }
    {
      int row = tid >> 1;
      int ko  = (tid & 1) * 16;
      union { uint4 u; u8 bvec[16]; } raw;
      raw.u = *(const uint4*)(Bbase + (size_t)row * 512 + kk + ko);
      ushort_t tmp[16];
#pragma unroll
      for (int i = 0; i < 16; i++) tmp[i] = raw.bvec[i] ? (ushort_t)0x3F80u : (ushort_t)0u;
      *(uint4*)&Bs[row][ko]     = *(uint4*)&tmp[0];
      *(uint4*)&Bs[row][ko + 8] = *(uint4*)&tmp[8];
    }
    __syncthreads();
    bf16x8 bfr[4];
#pragma unroll
    for (int j = 0; j < 4; j++) bfr[j] = *(const bf16x8*)&Bs[wcol + j * 16 + frow][fko];
#pragma unroll
    for (int p = 0; p < 3; p++) {
      bf16x8 af[4];
#pragma unroll
      for (int i = 0; i < 4; i++) af[i] = *(const bf16x8*)&As3[p][wrow + i * 16 + frow][fko];
#pragma unroll
      for (int i = 0; i < 4; i++)
#pragma unroll
        for (int j = 0; j < 4; j++)
          acc[i * 4 + j] = __builtin_amdgcn_mfma_f32_16x16x32_bf16(af[i], bfr[j], acc[i * 4 + j], 0, 0, 0);
    }
  }
  const int crow0 = (lane >> 4) * 4;
  const int cn    = lane & 15;
#pragma unroll
  for (int i = 0; i < 4; i++) {
#pragma unroll
    for (int r = 0; r < 4; r++) {
      int c = mt * 128 + wrow + i * 16 + crow0 + r;
      float scf = psc[c];
      float bif = pbi[c];
      float bpf = bp[c];
#pragma unroll
      for (int j = 0; j < 4; j++) {
        int n = nt * 128 + wcol + j * 16 + cn;
        size_t idx = ((size_t)tb * C_DIM + c) * N_DIM + n;
        out0[idx] = (acc[i * 4 + j][r] + bpf) * scf + bif + x[idx];
      }
    }
  }
}

// ---------------------------------------------------------------------------
// fp32 problem. d_out = 33,554,432 floats (134 MB): out0 [0,16.7M) floats,
// out1 (v) [16.7M,33.5M) floats. Scratch in the out0 byte region (dead until
// K5 fully overwrites it):
//   o0+0      xsT8 16MB [K1->K2]  (aliased by attn 8MB [K3->K4])
//   o0+16M    qs8  16MB [K2->K4]
//   o0+32M    ks8  16MB [K2->K3]
//   o0+48M    Wqkv split 4.5MB [K0->K2]      (out0 region is 67.1MB)
// d_ws: ws+0 x2sT8 16MB [K4->K5]; ws+16M Wp split 1.5MB [K0->K5]. Need 17.5MB.
// ---------------------------------------------------------------------------
extern "C" void kernel_launch(void* const* d_in, const int* in_sizes, int n_in,
                              void* d_out, int out_size, void* d_ws, size_t ws_size,
                              hipStream_t stream) {
  const float* x   = (const float*)d_in[0];
  const float* Wq  = (const float*)d_in[1];
  const float* qsc = (const float*)d_in[2];
  const float* qbi = (const float*)d_in[3];
  const float* Wk  = (const float*)d_in[4];
  const float* ksc = (const float*)d_in[5];
  const float* kbi = (const float*)d_in[6];
  const float* Wv  = (const float*)d_in[7];
  const float* vsc = (const float*)d_in[8];
  const float* vbi = (const float*)d_in[9];
  const float* Wp  = (const float*)d_in[10];
  const float* bp  = (const float*)d_in[11];
  const float* psc = (const float*)d_in[12];
  const float* pbi = (const float*)d_in[13];

  float* out0 = (float*)d_out;
  float* out1 = out0 + 16777216;   // v spikes [T,B,h,N,hd] fp32

  const size_t M16 = 16u * 1024u * 1024u;
  char* o0 = (char*)d_out;
  char* ws = (char*)d_ws;

  u8*       xsT8  = (u8*)(o0);
  u8*       qs8   = (u8*)(o0 + M16);
  u8*       ks8   = (u8*)(o0 + 2 * M16);
  ushort_t* Sqkv  = (ushort_t*)(o0 + 3 * M16);   // 4.5MB, ends at 52.5MB < 64MB
  float*    attn  = (float*)(o0);                // aliases xsT8 (dead after K2)
  u8*       x2sT8 = (u8*)(ws);                   // 16MB
  ushort_t* Sp    = (ushort_t*)(ws + M16);       // 1.5MB

  hipLaunchKernelGGL(k0_split,        dim3(512),       dim3(256), 0, stream,
                     Wq, Wk, Wv, Wp, Sqkv, Sp);
  hipLaunchKernelGGL(k1_shortcut_lif, dim3(4, 8, 32),  dim3(256), 0, stream, x, xsT8);
  hipLaunchKernelGGL(k2_qkv,          dim3(2, 12, 32), dim3(256), 0, stream,
                     xsT8, Sqkv, qsc, qbi, ksc, kbi, vsc, vbi, qs8, ks8, out1);
  hipLaunchKernelGGL(k3_attn,         dim3(8, 32, 2),  dim3(256), 0, stream, ks8, out1, attn);
  hipLaunchKernelGGL(k4_out_lif,      dim3(8, 32),     dim3(256), 0, stream, qs8, attn, x2sT8);
  hipLaunchKernelGGL(k5_proj,         dim3(2, 4, 128), dim3(256), 0, stream,
                     x2sT8, Sp, bp, psc, pbi, x, out0);
}

// Round 5
// 524.212 us; speedup vs baseline: 1.2252x; 1.2252x over previous
//
#include <hip/hip_runtime.h>

typedef unsigned short ushort_t;
typedef unsigned char u8;
typedef short bf16x8 __attribute__((ext_vector_type(8)));
typedef float f32x4 __attribute__((ext_vector_type(4)));

#define T_DIM 4
#define B_DIM 32
#define C_DIM 512
#define N_DIM 256

__device__ __forceinline__ float bf2f(ushort_t u) {
  union { unsigned int i; float f; } x;
  x.i = ((unsigned int)u) << 16;
  return x.f;
}
__device__ __forceinline__ ushort_t f2bf(float f) {
  unsigned int u = __float_as_uint(f);
  u = (u + 0x7FFFu + ((u >> 16) & 1u)) >> 16;
  return (ushort_t)u;
}

// ---------------------------------------------------------------------------
// K0: split fp32 weights into 3 bf16 planes (hi, mid, lo). W ~= hi+mid+lo.
// ---------------------------------------------------------------------------
__global__ __launch_bounds__(256) void k0_split(
    const float* __restrict__ Wq, const float* __restrict__ Wk,
    const float* __restrict__ Wv, const float* __restrict__ Wp,
    ushort_t* __restrict__ Sqkv, ushort_t* __restrict__ Sp)
{
  int gid = blockIdx.x * 256 + threadIdx.x;   // [0, 131072)
  int w = gid >> 15;
  int off = (gid & 32767) * 8;
  const float* src = (w == 0) ? Wq : ((w == 1) ? Wk : ((w == 2) ? Wv : Wp));
  ushort_t* dst = (w < 3) ? (Sqkv + (size_t)w * 3 * 262144) : Sp;
  float wv[8];
  *(float4*)&wv[0] = *(const float4*)(src + off);
  *(float4*)&wv[4] = *(const float4*)(src + off + 4);
  ushort_t hi[8], mi[8], lo[8];
#pragma unroll
  for (int i = 0; i < 8; i++) {
    float f = wv[i];
    ushort_t h = f2bf(f);  float r  = f - bf2f(h);
    ushort_t m = f2bf(r);  float r2 = r - bf2f(m);
    ushort_t l = f2bf(r2);
    hi[i] = h; mi[i] = m; lo[i] = l;
  }
  *(uint4*)(dst + off)              = *(uint4*)&hi[0];
  *(uint4*)(dst + 262144 + off)     = *(uint4*)&mi[0];
  *(uint4*)(dst + 2 * 262144 + off) = *(uint4*)&lo[0];
}

// ---------------------------------------------------------------------------
// K1: shortcut LIF on x [T,B,C,N] (fp32) -> spikes transposed xsT8 [T,B,N,C] u8
// ---------------------------------------------------------------------------
__global__ __launch_bounds__(256) void k1_shortcut_lif(
    const float* __restrict__ x, u8* __restrict__ xsT8)
{
  const int n0 = blockIdx.x * 64;
  const int c0 = blockIdx.y * 64;
  const int b  = blockIdx.z;
  __shared__ u8 sm[64][80];
  const int tid = threadIdx.x;
  const int r  = tid >> 2;
  const int j0 = (tid & 3) * 16;
  float v[16];
#pragma unroll
  for (int i = 0; i < 16; i++) v[i] = 0.f;
  for (int t = 0; t < T_DIM; t++) {
    const float* xp = x + ((((size_t)t * B_DIM + b) * C_DIM) + c0 + r) * N_DIM + n0 + j0;
    float xv[16];
    *(float4*)&xv[0]  = *(const float4*)xp;
    *(float4*)&xv[4]  = *(const float4*)(xp + 4);
    *(float4*)&xv[8]  = *(const float4*)(xp + 8);
    *(float4*)&xv[12] = *(const float4*)(xp + 12);
    __syncthreads();
#pragma unroll
    for (int i = 0; i < 16; i++) {
      float nv = v[i] + (xv[i] - v[i]) * 0.5f;
      bool s = (nv >= 1.0f);
      v[i] = s ? 0.f : nv;
      sm[j0 + i][r] = s ? (u8)1 : (u8)0;
    }
    __syncthreads();
    union { uint4 u; u8 b[16]; } ov;
#pragma unroll
    for (int i = 0; i < 16; i++) ov.b[i] = sm[r][j0 + i];
    u8* op = xsT8 + ((((size_t)t * B_DIM + b) * N_DIM) + n0 + r) * C_DIM + c0 + j0;
    *(uint4*)op = ov.u;
  }
}

// ---------------------------------------------------------------------------
// K2: QKV conv1x1 + BN + LIF. 512 threads (8 waves), 64m x 128n tile,
// double-buffered LDS (1 barrier/k-step) + register prefetch, XOR-swizzled LDS.
// Stacked M=1536 over 24 m-tiles of 64. t-loop fused (v-state in regs).
//    q -> qs8[t,b,c,n] u8 ; k -> ks8[t,b,c,n] u8
//    v -> vout[t,b,h,n,d] fp32 0/1 via full-line float4 stores.
// ---------------------------------------------------------------------------
__global__ __launch_bounds__(512, 4) void k2_qkv(
    const u8* __restrict__ xsT8, const ushort_t* __restrict__ Sqkv,
    const float* __restrict__ qsc, const float* __restrict__ qbi,
    const float* __restrict__ ksc, const float* __restrict__ kbi,
    const float* __restrict__ vsc, const float* __restrict__ vbi,
    u8* __restrict__ qs8, u8* __restrict__ ks8, float* __restrict__ vout)
{
  const int nt = blockIdx.x;          // 0..1
  const int mt = blockIdx.y;          // 0..23
  const int b  = blockIdx.z;          // 0..31
  const int branch = mt >> 3;         // 0=q 1=k 2=v
  const int mloc = (mt & 7) * 64;     // within branch's 512
  const ushort_t* Ws = Sqkv + (size_t)branch * 3 * 262144;
  const float* scp = (branch == 0) ? qsc : ((branch == 1) ? ksc : vsc);
  const float* bip = (branch == 0) ? qbi : ((branch == 1) ? kbi : vbi);

  __shared__ ushort_t As3[2][3][64][32];   // XOR-swizzled slots, no pad
  __shared__ ushort_t Bs[2][128][32];

  const int tid  = threadIdx.x;
  const int lane = tid & 63;
  const int wave = tid >> 6;
  const int wrow = (wave >> 1) * 16;  // m strip (16 rows)
  const int wcol = (wave & 1) * 64;   // n half
  const int frow = lane & 15;
  const int fsl  = lane >> 4;         // 16B slot index 0..3

  const u8* Bb0 = xsT8 + ((size_t)b * N_DIM + nt * 128) * C_DIM;  // + t*B*N*C

  // prefetch mapping
  const int ach0 = tid;          // A chunk 0 (all threads)
  const int ap0 = ach0 >> 8, ar0 = (ach0 & 255) >> 2, asl0 = ach0 & 3;
  const int ach1 = tid + 512;    // A chunk 1 (tid<256)
  const int ap1 = ach1 >> 8, ar1 = (ach1 & 255) >> 2, asl1 = ach1 & 3;
  const int brow = tid >> 1, bsl0 = (tid & 1) * 2;
  uint4 pa0, pa1, pb;

#define K2_LOAD(s_) { int t_ = (s_) >> 4; int kb_ = ((s_) & 15) * 32;                     \
    pa0 = *(const uint4*)(Ws + (size_t)ap0 * 262144 + (size_t)(mloc + ar0) * 512 + kb_ + asl0 * 8); \
    if (tid < 256) {                                                                       \
      pa1 = *(const uint4*)(Ws + (size_t)ap1 * 262144 + (size_t)(mloc + ar1) * 512 + kb_ + asl1 * 8); \
      pb  = *(const uint4*)(Bb0 + (size_t)t_ * B_DIM * N_DIM * C_DIM + (size_t)brow * 512 + kb_ + bsl0 * 8); \
    } }

#define K2_WRITE(buf_) {                                                                   \
    *(uint4*)&As3[buf_][ap0][ar0][(asl0 ^ ((ar0 >> 1) & 3)) * 8] = pa0;                    \
    if (tid < 256) {                                                                       \
      *(uint4*)&As3[buf_][ap1][ar1][(asl1 ^ ((ar1 >> 1) & 3)) * 8] = pa1;                  \
      union { uint4 u; u8 bb[16]; } rw_; rw_.u = pb;                                       \
      ushort_t tmp_[16];                                                                   \
      _Pragma("unroll") for (int z_ = 0; z_ < 16; z_++) tmp_[z_] = rw_.bb[z_] ? (ushort_t)0x3F80u : (ushort_t)0u; \
      int sw_ = (brow >> 1) & 3;                                                           \
      *(uint4*)&Bs[buf_][brow][((bsl0) ^ sw_) * 8]     = *(uint4*)&tmp_[0];                \
      *(uint4*)&Bs[buf_][brow][((bsl0 + 1) ^ sw_) * 8] = *(uint4*)&tmp_[8];                \
    } }

  f32x4 acc[4];
  float vst[16];
#pragma unroll
  for (int i = 0; i < 16; i++) vst[i] = 0.f;
#pragma unroll
  for (int i = 0; i < 4; i++) acc[i] = (f32x4){0.f, 0.f, 0.f, 0.f};

  // preload BN scale/bias for this thread's 4 c-rows (c constant across t)
  const int crow0 = (lane >> 4) * 4;
  const int cn    = lane & 15;
  float sc4[4], bi4[4];
#pragma unroll
  for (int r = 0; r < 4; r++) {
    int c = mloc + wrow + crow0 + r;
    sc4[r] = scp[c]; bi4[r] = bip[c];
  }

  K2_LOAD(0); K2_WRITE(0); __syncthreads();

  for (int s = 0; s < 64; s++) {
    const int cur = s & 1;
    if (s < 63) K2_LOAD(s + 1);
    // B frags (shared across planes)
    bf16x8 bfr[4];
#pragma unroll
    for (int j = 0; j < 4; j++) {
      int row = wcol + j * 16 + frow;
      bfr[j] = *(const bf16x8*)&Bs[cur][row][(fsl ^ ((row >> 1) & 3)) * 8];
    }
    int arow = wrow + frow;
    int asw  = (fsl ^ ((arow >> 1) & 3)) * 8;
#pragma unroll
    for (int p = 0; p < 3; p++) {
      bf16x8 af = *(const bf16x8*)&As3[cur][p][arow][asw];
#pragma unroll
      for (int j = 0; j < 4; j++)
        acc[j] = __builtin_amdgcn_mfma_f32_16x16x32_bf16(af, bfr[j], acc[j], 0, 0, 0);
    }
    if (s < 63) K2_WRITE((s + 1) & 1);
    __syncthreads();

    if ((s & 15) == 15) {
      // epilogue for t = s>>4
      const int t = s >> 4;
      const size_t tb = (size_t)t * B_DIM + b;
      if (branch < 2) {
        u8* dst = (branch == 0) ? qs8 : ks8;
#pragma unroll
        for (int r = 0; r < 4; r++) {
          int c = mloc + wrow + crow0 + r;
#pragma unroll
          for (int j = 0; j < 4; j++) {
            int n = nt * 128 + wcol + j * 16 + cn;
            float y = acc[j][r] * sc4[r] + bi4[r];
            int vi = j * 4 + r;
            float v = vst[vi];
            v = v + (y - v) * 0.5f;
            bool sp = (v >= 1.0f);
            vst[vi] = sp ? 0.f : v;
            dst[(tb * C_DIM + c) * N_DIM + n] = sp ? (u8)1 : (u8)0;
          }
        }
      } else {
        const int hv = mloc >> 6;
        const int d0 = wrow + crow0;
#pragma unroll
        for (int j = 0; j < 4; j++) {
          int n = nt * 128 + wcol + j * 16 + cn;
          float4 o;
          float ov[4];
#pragma unroll
          for (int r = 0; r < 4; r++) {
            float y = acc[j][r] * sc4[r] + bi4[r];
            int vi = j * 4 + r;
            float v = vst[vi];
            v = v + (y - v) * 0.5f;
            bool sp = (v >= 1.0f);
            vst[vi] = sp ? 0.f : v;
            ov[r] = sp ? 1.0f : 0.0f;
          }
          o.x = ov[0]; o.y = ov[1]; o.z = ov[2]; o.w = ov[3];
          *(float4*)(vout + ((tb * 8 + hv) * N_DIM + n) * 64 + d0) = o;
        }
      }
#pragma unroll
      for (int i = 0; i < 4; i++) acc[i] = (f32x4){0.f, 0.f, 0.f, 0.f};
    }
  }
#undef K2_LOAD
#undef K2_WRITE
}

// ---------------------------------------------------------------------------
// K3: attn[ch,b,h,d,e] = (1/16) * sum_{t,n} k[d,(t,n)] * v[(t,n),e]
// ---------------------------------------------------------------------------
__global__ __launch_bounds__(256) void k3_attn(
    const u8* __restrict__ ks8, const float* __restrict__ vsp,
    float* __restrict__ attn)
{
  const int h  = blockIdx.x;
  const int b  = blockIdx.y;
  const int ch = blockIdx.z;
  __shared__ u8 KtT[64][80];
  __shared__ u8 Vt[64][80];
  const int tid = threadIdx.x;
  const int d0 = (tid >> 4) * 4;
  const int e0 = (tid & 15) * 4;
  float a[16];
#pragma unroll
  for (int i = 0; i < 16; i++) a[i] = 0.f;

  for (int tt = 0; tt < 2; tt++) {
    int t = ch * 2 + tt;
    for (int n0 = 0; n0 < 256; n0 += 64) {
      __syncthreads();
      {
        int d  = tid >> 2;
        int s0 = (tid & 3) * 16;
        union { uint4 u; u8 bvec[16]; } kb;
        kb.u = *(const uint4*)(ks8 + ((((size_t)t * B_DIM + b) * C_DIM) + h * 64 + d) * N_DIM + n0 + s0);
#pragma unroll
        for (int i = 0; i < 16; i++) KtT[s0 + i][d] = kb.bvec[i];
      }
      {
        const float* vb = vsp + ((((size_t)t * B_DIM + b) * 8 + h) * N_DIM + n0) * 64;
#pragma unroll
        for (int u = 0; u < 4; u++) {
          int chunk = tid + u * 256;
          int row = chunk >> 4;
          int eo  = (chunk & 15) * 4;
          float4 v4 = *(const float4*)(vb + (size_t)row * 64 + eo);
          Vt[row][eo + 0] = (u8)(v4.x != 0.f);
          Vt[row][eo + 1] = (u8)(v4.y != 0.f);
          Vt[row][eo + 2] = (u8)(v4.z != 0.f);
          Vt[row][eo + 3] = (u8)(v4.w != 0.f);
        }
      }
      __syncthreads();
      for (int s = 0; s < 64; s++) {
        uchar4 kb = *(const uchar4*)&KtT[s][d0];
        float kv[4] = { (float)kb.x, (float)kb.y, (float)kb.z, (float)kb.w };
        uchar4 vr = *(const uchar4*)&Vt[s][e0];
        float vv[4] = { (float)vr.x, (float)vr.y, (float)vr.z, (float)vr.w };
#pragma unroll
        for (int i = 0; i < 4; i++)
#pragma unroll
          for (int j = 0; j < 4; j++) a[i * 4 + j] += kv[i] * vv[j];
      }
    }
  }
  float* ap = attn + ((((size_t)ch * B_DIM + b) * 8 + h) * 64 + d0) * 64 + e0;
#pragma unroll
  for (int i = 0; i < 4; i++)
#pragma unroll
    for (int j = 0; j < 4; j++)
      ap[i * 64 + j] = a[i * 4 + j] * 0.0625f;
}

// ---------------------------------------------------------------------------
// K4: out[e,n] = sum_d attn[d,e]*q[d,n], attn-LIF(0.5) -> x2sT8[t,b,n,c] u8.
// n-chunk split across grid.z for 4x parallelism; vst[16] per thread.
// ---------------------------------------------------------------------------
__global__ __launch_bounds__(256) void k4_out_lif(
    const u8* __restrict__ qs8, const float* __restrict__ attn,
    u8* __restrict__ x2sT8)
{
  const int h  = blockIdx.x;
  const int b  = blockIdx.y;
  const int nc = blockIdx.z;   // 0..3
  __shared__ float At[64][68];
  __shared__ u8 Qt[64][80];
  const int tid = threadIdx.x;
  const int e0 = (tid >> 4) * 4;
  const int n0 = (tid & 15) * 4;
  float vst[16];
#pragma unroll
  for (int i = 0; i < 16; i++) vst[i] = 0.f;

  for (int t = 0; t < T_DIM; t++) {
    if ((t & 1) == 0) {
      __syncthreads();
      const float* ap = attn + ((((size_t)(t >> 1) * B_DIM + b) * 8) + h) * 4096;
      int dr = tid >> 2;
      int co = (tid & 3) * 16;
#pragma unroll
      for (int u = 0; u < 4; u++)
        *(float4*)&At[dr][co + u * 4] = *(const float4*)(ap + dr * 64 + co + u * 4);
    }
    __syncthreads();
    {
      int d  = tid >> 2;
      int so = (tid & 3) * 16;
      *(uint4*)&Qt[d][so] =
        *(const uint4*)(qs8 + ((((size_t)t * B_DIM + b) * C_DIM) + h * 64 + d) * N_DIM + nc * 64 + so);
    }
    __syncthreads();
    float acc[16];
#pragma unroll
    for (int i = 0; i < 16; i++) acc[i] = 0.f;
    for (int d = 0; d < 64; d++) {
      float4 av = *(const float4*)&At[d][e0];
      float avv[4] = { av.x, av.y, av.z, av.w };
      uchar4 qr = *(const uchar4*)&Qt[d][n0];
      float qv[4] = { (float)qr.x, (float)qr.y, (float)qr.z, (float)qr.w };
#pragma unroll
      for (int i = 0; i < 4; i++)
#pragma unroll
        for (int j = 0; j < 4; j++) acc[i * 4 + j] += avv[i] * qv[j];
    }
#pragma unroll
    for (int j = 0; j < 4; j++) {
      u8 sv[4];
#pragma unroll
      for (int i = 0; i < 4; i++) {
        int vi = i * 4 + j;
        float y = acc[i * 4 + j];
        float nv = vst[vi] + (y - vst[vi]) * 0.5f;
        bool s = (nv >= 0.5f);
        vst[vi] = s ? 0.f : nv;
        sv[i] = s ? (u8)1 : (u8)0;
      }
      int n = nc * 64 + n0 + j;
      u8* op = x2sT8 + ((((size_t)t * B_DIM + b) * N_DIM) + n) * C_DIM + h * 64 + e0;
      *(uchar4*)op = make_uchar4(sv[0], sv[1], sv[2], sv[3]);
    }
  }
}

// ---------------------------------------------------------------------------
// K5: proj conv1x1 (+bp)*scale+bias + residual -> out0 fp32. Same engine as
// K2: 512 threads, 64m x 128n, double-buffered, XOR-swizzled, reg prefetch.
// ---------------------------------------------------------------------------
__global__ __launch_bounds__(512, 4) void k5_proj(
    const u8* __restrict__ x2sT8, const ushort_t* __restrict__ Sp,
    const float* __restrict__ bp, const float* __restrict__ psc,
    const float* __restrict__ pbi,
    const float* __restrict__ x, float* __restrict__ out0)
{
  const int nt = blockIdx.x;   // 0..1
  const int mt = blockIdx.y;   // 0..7
  const int tb = blockIdx.z;   // 0..127
  const int mloc = mt * 64;

  __shared__ ushort_t As3[2][3][64][32];
  __shared__ ushort_t Bs[2][128][32];

  const int tid  = threadIdx.x;
  const int lane = tid & 63;
  const int wave = tid >> 6;
  const int wrow = (wave >> 1) * 16;
  const int wcol = (wave & 1) * 64;
  const int frow = lane & 15;
  const int fsl  = lane >> 4;

  const u8* Bb = x2sT8 + ((size_t)tb * N_DIM + nt * 128) * C_DIM;

  const int ach0 = tid;
  const int ap0 = ach0 >> 8, ar0 = (ach0 & 255) >> 2, asl0 = ach0 & 3;
  const int ach1 = tid + 512;
  const int ap1 = ach1 >> 8, ar1 = (ach1 & 255) >> 2, asl1 = ach1 & 3;
  const int brow = tid >> 1, bsl0 = (tid & 1) * 2;
  uint4 pa0, pa1, pb;

#define K5_LOAD(s_) { int kb_ = (s_) * 32;                                                 \
    pa0 = *(const uint4*)(Sp + (size_t)ap0 * 262144 + (size_t)(mloc + ar0) * 512 + kb_ + asl0 * 8); \
    if (tid < 256) {                                                                       \
      pa1 = *(const uint4*)(Sp + (size_t)ap1 * 262144 + (size_t)(mloc + ar1) * 512 + kb_ + asl1 * 8); \
      pb  = *(const uint4*)(Bb + (size_t)brow * 512 + kb_ + bsl0 * 8);                     \
    } }

#define K5_WRITE(buf_) {                                                                   \
    *(uint4*)&As3[buf_][ap0][ar0][(asl0 ^ ((ar0 >> 1) & 3)) * 8] = pa0;                    \
    if (tid < 256) {                                                                       \
      *(uint4*)&As3[buf_][ap1][ar1][(asl1 ^ ((ar1 >> 1) & 3)) * 8] = pa1;                  \
      union { uint4 u; u8 bb[16]; } rw_; rw_.u = pb;                                       \
      ushort_t tmp_[16];                                                                   \
      _Pragma("unroll") for (int z_ = 0; z_ < 16; z_++) tmp_[z_] = rw_.bb[z_] ? (ushort_t)0x3F80u : (ushort_t)0u; \
      int sw_ = (brow >> 1) & 3;                                                           \
      *(uint4*)&Bs[buf_][brow][((bsl0) ^ sw_) * 8]     = *(uint4*)&tmp_[0];                \
      *(uint4*)&Bs[buf_][brow][((bsl0 + 1) ^ sw_) * 8] = *(uint4*)&tmp_[8];                \
    } }

  f32x4 acc[4];
#pragma unroll
  for (int i = 0; i < 4; i++) acc[i] = (f32x4){0.f, 0.f, 0.f, 0.f};

  K5_LOAD(0); K5_WRITE(0); __syncthreads();

  for (int s = 0; s < 16; s++) {
    const int cur = s & 1;
    if (s < 15) K5_LOAD(s + 1);
    bf16x8 bfr[4];
#pragma unroll
    for (int j = 0; j < 4; j++) {
      int row = wcol + j * 16 + frow;
      bfr[j] = *(const bf16x8*)&Bs[cur][row][(fsl ^ ((row >> 1) & 3)) * 8];
    }
    int arow = wrow + frow;
    int asw  = (fsl ^ ((arow >> 1) & 3)) * 8;
#pragma unroll
    for (int p = 0; p < 3; p++) {
      bf16x8 af = *(const bf16x8*)&As3[cur][p][arow][asw];
#pragma unroll
      for (int j = 0; j < 4; j++)
        acc[j] = __builtin_amdgcn_mfma_f32_16x16x32_bf16(af, bfr[j], acc[j], 0, 0, 0);
    }
    if (s < 15) K5_WRITE((s + 1) & 1);
    __syncthreads();
  }

  const int crow0 = (lane >> 4) * 4;
  const int cn    = lane & 15;
#pragma unroll
  for (int r = 0; r < 4; r++) {
    int c = mloc + wrow + crow0 + r;
    float scf = psc[c];
    float bif = pbi[c];
    float bpf = bp[c];
#pragma unroll
    for (int j = 0; j < 4; j++) {
      int n = nt * 128 + wcol + j * 16 + cn;
      size_t idx = ((size_t)tb * C_DIM + c) * N_DIM + n;
      out0[idx] = (acc[j][r] + bpf) * scf + bif + x[idx];
    }
  }
#undef K5_LOAD
#undef K5_WRITE
}

// ---------------------------------------------------------------------------
// fp32 problem. d_out = 33,554,432 floats: out0 [0,16.7M), out1 [16.7M,33.5M).
// Scratch in out0 byte region (dead until K5 overwrites it):
//   o0+0    xsT8 16MB [K1->K2]  (aliased by attn 8MB [K3->K4])
//   o0+16M  qs8 16MB [K2->K4] ; o0+32M ks8 16MB [K2->K3]
//   o0+48M  Sqkv split 4.5MB [K0->K2]
// d_ws: x2sT8 16MB [K4->K5]; +16M Sp split 1.5MB [K0->K5].
// ---------------------------------------------------------------------------
extern "C" void kernel_launch(void* const* d_in, const int* in_sizes, int n_in,
                              void* d_out, int out_size, void* d_ws, size_t ws_size,
                              hipStream_t stream) {
  const float* x   = (const float*)d_in[0];
  const float* Wq  = (const float*)d_in[1];
  const float* qsc = (const float*)d_in[2];
  const float* qbi = (const float*)d_in[3];
  const float* Wk  = (const float*)d_in[4];
  const float* ksc = (const float*)d_in[5];
  const float* kbi = (const float*)d_in[6];
  const float* Wv  = (const float*)d_in[7];
  const float* vsc = (const float*)d_in[8];
  const float* vbi = (const float*)d_in[9];
  const float* Wp  = (const float*)d_in[10];
  const float* bp  = (const float*)d_in[11];
  const float* psc = (const float*)d_in[12];
  const float* pbi = (const float*)d_in[13];

  float* out0 = (float*)d_out;
  float* out1 = out0 + 16777216;

  const size_t M16 = 16u * 1024u * 1024u;
  char* o0 = (char*)d_out;
  char* ws = (char*)d_ws;

  u8*       xsT8  = (u8*)(o0);
  u8*       qs8   = (u8*)(o0 + M16);
  u8*       ks8   = (u8*)(o0 + 2 * M16);
  ushort_t* Sqkv  = (ushort_t*)(o0 + 3 * M16);
  float*    attn  = (float*)(o0);
  u8*       x2sT8 = (u8*)(ws);
  ushort_t* Sp    = (ushort_t*)(ws + M16);

  hipLaunchKernelGGL(k0_split,        dim3(512),        dim3(256), 0, stream,
                     Wq, Wk, Wv, Wp, Sqkv, Sp);
  hipLaunchKernelGGL(k1_shortcut_lif, dim3(4, 8, 32),   dim3(256), 0, stream, x, xsT8);
  hipLaunchKernelGGL(k2_qkv,          dim3(2, 24, 32),  dim3(512), 0, stream,
                     xsT8, Sqkv, qsc, qbi, ksc, kbi, vsc, vbi, qs8, ks8, out1);
  hipLaunchKernelGGL(k3_attn,         dim3(8, 32, 2),   dim3(256), 0, stream, ks8, out1, attn);
  hipLaunchKernelGGL(k4_out_lif,      dim3(8, 32, 4),   dim3(256), 0, stream, qs8, attn, x2sT8);
  hipLaunchKernelGGL(k5_proj,         dim3(2, 8, 128),  dim3(512), 0, stream,
                     x2sT8, Sp, bp, psc, pbi, x, out0);
}